// Round 6
// baseline (212.985 us; speedup 1.0000x reference)
//
#include <hip/hip_runtime.h>
#include <math.h>

#define T_N 2097152
#define NB 2048                // scan/main grid: 8 blocks/CU worth of work
#define NT 256
#define EPT 4
#define CHUNK (NT * EPT)       // 1024 elements per block
#define GPT (NB / NT)          // 8 block-summaries per thread in k_carry
#define GAMMA_F 0.99f
#define GL_F (0.99f * 0.95f)
#define LOG2PI_F 1.8378770664093453f

// ws layout (every slot rewritten each launch -> poison-safe):
//   ws +      0 : float stats[4]  (mean_a, inv_a, mean_r, inv_r)
//   ws +    256 : float4 blk[NB*4]   extended block summaries (14 floats padded to 16)
//   ws + 131328 : float2 car[NB]     per-block entering carries (ret, adv)
//   ws + 147712 : float2 lblk[NB]    per-block loss partials (actor, critic)

// ---------------- affine (A,B) pair for both recurrences (k_main) ----------------
struct Aff4 { float ar, br, aa, ba; };
__device__ __forceinline__ Aff4 aff_id() { Aff4 o; o.ar = 1.f; o.br = 0.f; o.aa = 1.f; o.ba = 0.f; return o; }
// L is earlier in time (applied second in the reverse scan): (L o R)(y) = L(R(y))
__device__ __forceinline__ Aff4 aff_compose(const Aff4& L, const Aff4& R) {
    Aff4 o;
    o.ar = L.ar * R.ar;  o.br = fmaf(L.ar, R.br, L.br);
    o.aa = L.aa * R.aa;  o.ba = fmaf(L.aa, R.ba, L.ba);
    return o;
}
__device__ __forceinline__ Aff4 aff_shfl_down(const Aff4& x, int s) {
    Aff4 o;
    o.ar = __shfl_down(x.ar, s, 64); o.br = __shfl_down(x.br, s, 64);
    o.aa = __shfl_down(x.aa, s, 64); o.ba = __shfl_down(x.ba, s, 64);
    return o;
}
__device__ __forceinline__ Aff4 aff_wave_suffix(Aff4 x, int lane) {
#pragma unroll
    for (int s = 1; s < 64; s <<= 1) {
        Aff4 o = aff_shfl_down(x, s);
        if (lane + s < 64) x = aff_compose(x, o);
    }
    return x;
}

// ------------- extended segment: y-map + running sum + running sum-of-squares -------------
// y_out = A*y + B ; Sum(y_t) = P*y + S ; Sum(y_t^2) = U*y^2 + 2*V*y + Q   (y = incoming state)
// identity (empty segment): A=1,B=0, P=S=U=V=Q=0
struct SegF { float A, B, P, S, U, V, Q; };
struct Seg2F { SegF r, a; };
struct SegD { double A, B, P, S, U, V, Q; };
struct Seg2D { SegD r, a; };

__device__ __forceinline__ SegF segf_compose(const SegF& L, const SegF& R) {
    SegF o;
    o.A = L.A * R.A;
    o.B = fmaf(L.A, R.B, L.B);
    o.P = fmaf(L.P, R.A, R.P);
    o.S = fmaf(L.P, R.B, R.S) + L.S;
    float A2 = R.A * R.A, AB = R.A * R.B, B2 = R.B * R.B;
    o.U = fmaf(L.U, A2, R.U);
    o.V = fmaf(L.U, AB, fmaf(L.V, R.A, R.V));
    o.Q = fmaf(L.U, B2, fmaf(2.f * L.V, R.B, R.Q)) + L.Q;
    return o;
}
__device__ __forceinline__ Seg2F seg2f_compose(const Seg2F& L, const Seg2F& R) {
    Seg2F o; o.r = segf_compose(L.r, R.r); o.a = segf_compose(L.a, R.a); return o;
}
__device__ __forceinline__ SegF segf_shfl_down(const SegF& x, int s) {
    SegF o;
    o.A = __shfl_down(x.A, s, 64); o.B = __shfl_down(x.B, s, 64);
    o.P = __shfl_down(x.P, s, 64); o.S = __shfl_down(x.S, s, 64);
    o.U = __shfl_down(x.U, s, 64); o.V = __shfl_down(x.V, s, 64);
    o.Q = __shfl_down(x.Q, s, 64);
    return o;
}
__device__ __forceinline__ Seg2F seg2f_shfl_down(const Seg2F& x, int s) {
    Seg2F o; o.r = segf_shfl_down(x.r, s); o.a = segf_shfl_down(x.a, s); return o;
}

__device__ __forceinline__ SegD segd_id() { SegD o; o.A = 1.0; o.B = 0.0; o.P = 0.0; o.S = 0.0; o.U = 0.0; o.V = 0.0; o.Q = 0.0; return o; }
__device__ __forceinline__ SegD segd_compose(const SegD& L, const SegD& R) {
    SegD o;
    o.A = L.A * R.A;
    o.B = fma(L.A, R.B, L.B);
    o.P = fma(L.P, R.A, R.P);
    o.S = fma(L.P, R.B, R.S) + L.S;
    double A2 = R.A * R.A, AB = R.A * R.B, B2 = R.B * R.B;
    o.U = fma(L.U, A2, R.U);
    o.V = fma(L.U, AB, fma(L.V, R.A, R.V));
    o.Q = fma(L.U, B2, fma(2.0 * L.V, R.B, R.Q)) + L.Q;
    return o;
}
__device__ __forceinline__ Seg2D seg2d_id() { Seg2D o; o.r = segd_id(); o.a = segd_id(); return o; }
__device__ __forceinline__ Seg2D seg2d_compose(const Seg2D& L, const Seg2D& R) {
    Seg2D o; o.r = segd_compose(L.r, R.r); o.a = segd_compose(L.a, R.a); return o;
}
__device__ __forceinline__ SegD segd_shfl_down(const SegD& x, int s) {
    SegD o;
    o.A = __shfl_down(x.A, s, 64); o.B = __shfl_down(x.B, s, 64);
    o.P = __shfl_down(x.P, s, 64); o.S = __shfl_down(x.S, s, 64);
    o.U = __shfl_down(x.U, s, 64); o.V = __shfl_down(x.V, s, 64);
    o.Q = __shfl_down(x.Q, s, 64);
    return o;
}
__device__ __forceinline__ Seg2D seg2d_shfl_down(const Seg2D& x, int s) {
    Seg2D o; o.r = segd_shfl_down(x.r, s); o.a = segd_shfl_down(x.a, s); return o;
}

// Affine-only thread transform over EPT contiguous elements (right-to-left).
__device__ __forceinline__ Aff4 thread_transform(const float rr[EPT], const float vv[EPT],
                                                 const float mm[EPT], float vnext) {
    Aff4 x = aff_id();
    float vn = vnext;
#pragma unroll
    for (int j = EPT - 1; j >= 0; --j) {
        float m = mm[j];
        float gm = GAMMA_F * m;
        x.br = fmaf(gm, x.br, rr[j]);  x.ar = gm * x.ar;              // ret: y = gm*y + r
        float delta = fmaf(GAMMA_F * vn, m, rr[j]) - vv[j];
        float gl = GL_F * m;
        x.ba = fmaf(gl, x.ba, delta);  x.aa = gl * x.aa;              // adv: y = gl*y + delta
        vn = vv[j];
    }
    return x;
}

__device__ __forceinline__ void load4(const float* __restrict__ rew,
                                      const float* __restrict__ val,
                                      const int* __restrict__ msk, int g,
                                      float rr[EPT], float vv[EPT], float mm[EPT],
                                      float& vnext) {
    float4 r4 = *(const float4*)(rew + g);
    float4 v4 = *(const float4*)(val + g);
    int4 m4 = *(const int4*)(msk + g);
    vnext = (g + EPT < T_N) ? val[g + EPT] : 0.f;
    rr[0] = r4.x; rr[1] = r4.y; rr[2] = r4.z; rr[3] = r4.w;
    vv[0] = v4.x; vv[1] = v4.y; vv[2] = v4.z; vv[3] = v4.w;
    mm[0] = (float)m4.x; mm[1] = (float)m4.y; mm[2] = (float)m4.z; mm[3] = (float)m4.w;
}

// ============ K1: extended block summaries ============
__global__ __launch_bounds__(NT, 4) void k_summ(const float* __restrict__ rew,
                                                const float* __restrict__ val,
                                                const int* __restrict__ msk,
                                                float4* __restrict__ blk) {
    int tid = threadIdx.x, lane = tid & 63, wv = tid >> 6;
    int g = blockIdx.x * CHUNK + tid * EPT;
    float rr[EPT], vv[EPT], mm[EPT], vnext;
    load4(rew, val, msk, g, rr, vv, mm, vnext);
    // build thread's extended segment (right-to-left; element earlier in time is L)
    Seg2F x;
    x.r.A = 1.f; x.r.B = 0.f; x.r.P = 0.f; x.r.S = 0.f; x.r.U = 0.f; x.r.V = 0.f; x.r.Q = 0.f;
    x.a = x.r;
    float vn = vnext;
#pragma unroll
    for (int j = EPT - 1; j >= 0; --j) {
        float m = mm[j];
        float ar = GAMMA_F * m, br = rr[j];
        float aa = GL_F * m;
        float delta = fmaf(GAMMA_F * vn, m, rr[j]) - vv[j];
        Seg2F e;
        e.r.A = ar; e.r.B = br; e.r.P = ar; e.r.S = br; e.r.U = ar * ar; e.r.V = ar * br; e.r.Q = br * br;
        e.a.A = aa; e.a.B = delta; e.a.P = aa; e.a.S = delta; e.a.U = aa * aa; e.a.V = aa * delta; e.a.Q = delta * delta;
        x = seg2f_compose(e, x);
        vn = vv[j];
    }
    // ordered wave reduction (lane 0 ends with composition of lanes [0,64))
#pragma unroll
    for (int s = 1; s < 64; s <<= 1) {
        Seg2F o = seg2f_shfl_down(x, s);
        x = seg2f_compose(x, o);     // lane i earlier in time than lane i+s
    }
    __shared__ Seg2F sW[4];
    if (lane == 0) sW[wv] = x;
    __syncthreads();
    if (tid == 0) {
        Seg2F t = sW[3];
        t = seg2f_compose(sW[2], t);
        t = seg2f_compose(sW[1], t);
        t = seg2f_compose(sW[0], t);
        int b4 = blockIdx.x * 4;
        blk[b4 + 0] = make_float4(t.r.A, t.r.B, t.r.P, t.r.S);
        blk[b4 + 1] = make_float4(t.r.U, t.r.V, t.r.Q, t.a.A);
        blk[b4 + 2] = make_float4(t.a.B, t.a.P, t.a.S, t.a.U);
        blk[b4 + 3] = make_float4(t.a.V, t.a.Q, 0.f, 0.f);
    }
}

__device__ __forceinline__ Seg2D load_seg(const float4* __restrict__ blk, int idx) {
    float4 q0 = blk[idx * 4 + 0], q1 = blk[idx * 4 + 1];
    float4 q2 = blk[idx * 4 + 2], q3 = blk[idx * 4 + 3];
    Seg2D s;
    s.r.A = q0.x; s.r.B = q0.y; s.r.P = q0.z; s.r.S = q0.w;
    s.r.U = q1.x; s.r.V = q1.y; s.r.Q = q1.z; s.a.A = q1.w;
    s.a.B = q2.x; s.a.P = q2.y; s.a.S = q2.z; s.a.U = q2.w;
    s.a.V = q3.x; s.a.Q = q3.y;
    return s;
}

// ============ K2: single-block carry scan + global stats (f64) ============
__global__ __launch_bounds__(NT) void k_carry(const float4* __restrict__ blk,
                                              float2* __restrict__ car,
                                              float* __restrict__ stats) {
    int tid = threadIdx.x, lane = tid & 63, wv = tid >> 6;
    // pass 1: compose this thread's GPT consecutive block summaries (f64)
    Seg2D gc = seg2d_id();
#pragma unroll
    for (int p = GPT - 1; p >= 0; --p) gc = seg2d_compose(load_seg(blk, tid * GPT + p), gc);
    // inclusive suffix scan across wave
    Seg2D incl = gc;
#pragma unroll
    for (int s = 1; s < 64; s <<= 1) {
        Seg2D o = seg2d_shfl_down(incl, s);
        if (lane + s < 64) incl = seg2d_compose(incl, o);
    }
    // exclusive-within-wave
    Seg2D ex = seg2d_shfl_down(incl, 1);
    if (lane == 63) ex = seg2d_id();
    __shared__ Seg2D sW[4];
    if (lane == 0) sW[wv] = incl;
    __syncthreads();
    Seg2D tail = seg2d_id();
    for (int w = 3; w > wv; --w) tail = seg2d_compose(sW[w], tail);
    Seg2D H = seg2d_compose(ex, tail);   // composition of all summaries after this thread's group
    // pass 2: unwind per-block carries (reload summaries from L2)
#pragma unroll
    for (int p = GPT - 1; p >= 0; --p) {
        car[tid * GPT + p] = make_float2((float)H.r.B, (float)H.a.B);  // carry entering block = H(0)
        H = seg2d_compose(load_seg(blk, tid * GPT + p), H);
    }
    if (tid == 0) {
        Seg2D tot = seg2d_compose(incl, tail);   // full composition; y_in = 0
        const double Td = (double)T_N;
        double Sa = tot.a.S, Qa = tot.a.Q, Sr = tot.r.S, Qr = tot.r.Q;
        double va = (Qa - Sa * Sa / Td) / (Td - 1.0);
        double vr = (Qr - Sr * Sr / Td) / (Td - 1.0);
        stats[0] = (float)(Sa / Td);
        stats[1] = (float)(1.0 / (sqrt(va) + 1e-10));
        stats[2] = (float)(Sr / Td);
        stats[3] = (float)(1.0 / (sqrt(vr) + 1e-10));
    }
}

// ============ K3: scan redo (L3-hot) + fused loss — adv/ret never hit memory ============
__global__ __launch_bounds__(NT, 4) void k_main(const float* __restrict__ rew,
                                                const float* __restrict__ val,
                                                const int* __restrict__ msk,
                                                const float4* __restrict__ act,
                                                const float4* __restrict__ mu,
                                                const float4* __restrict__ lv,
                                                const float4* __restrict__ blp,
                                                const float2* __restrict__ car,
                                                const float* __restrict__ stats,
                                                float2* __restrict__ lblk) {
    int tid = threadIdx.x, lane = tid & 63, wv = tid >> 6;
    int b = blockIdx.x;
    int g = b * CHUNK + tid * EPT;
    float rr[EPT], vv[EPT], mm[EPT], vnext;
    load4(rew, val, msk, g, rr, vv, mm, vnext);
    Aff4 x = thread_transform(rr, vv, mm, vnext);
    Aff4 incl = aff_wave_suffix(x, lane);
    Aff4 ex = aff_shfl_down(incl, 1);
    if (lane == 63) ex = aff_id();
    __shared__ Aff4 sW[4];
    if (lane == 0) sW[wv] = incl;
    __syncthreads();
    Aff4 tail = aff_id();
    for (int w = 3; w > wv; --w) tail = aff_compose(sW[w], tail);
    ex = aff_compose(ex, tail);
    float2 c = car[b];
    float yr = fmaf(ex.ar, c.x, ex.br);
    float ya = fmaf(ex.aa, c.y, ex.ba);
    float retj[EPT], advj[EPT];
    float vn = vnext;
#pragma unroll
    for (int j = EPT - 1; j >= 0; --j) {
        float m = mm[j];
        float gm = GAMMA_F * m;
        yr = fmaf(gm, yr, rr[j]);  retj[j] = yr;
        float delta = fmaf(GAMMA_F * vn, m, rr[j]) - vv[j];
        ya = fmaf(GL_F * m, ya, delta);  advj[j] = ya;
        vn = vv[j];
    }
    float mean_a = stats[0], inv_a = stats[1], mean_r = stats[2], inv_r = stats[3];
    float aacc = 0.f, cacc = 0.f;
#pragma unroll
    for (int j = 0; j < EPT; ++j) {
        int t = g + j;
        float4 a = act[t], m = mu[t], l = lv[t], bb = blp[t];
        float x0 = -0.5f * (a.x - m.x) * (a.x - m.x) * expf(-l.x) - 0.5f * l.x;
        float x1 = -0.5f * (a.y - m.y) * (a.y - m.y) * expf(-l.y) - 0.5f * l.y;
        float x2 = -0.5f * (a.z - m.z) * (a.z - m.z) * expf(-l.z) - 0.5f * l.z;
        float x3 = -0.5f * (a.w - m.w) * (a.w - m.w) * expf(-l.w) - 0.5f * l.w;
        float X = (x0 + x1 + x2 + x3) - (bb.x + bb.y + bb.z + bb.w) - 2.f * LOG2PI_F;
        float ratio = expf(X);
        float rc = fminf(fmaxf(ratio, 0.8f), 1.2f);
        float an = (advj[j] - mean_a) * inv_a;
        aacc += fminf(ratio * an, rc * an);
        float rn = (retj[j] - mean_r) * inv_r;
        float d = vv[j] - rn;
        float adx = fabsf(d);
        cacc += (adx < 1.f) ? 0.5f * d * d : adx - 0.5f;
    }
#pragma unroll
    for (int s = 32; s > 0; s >>= 1) {
        aacc += __shfl_xor(aacc, s, 64);
        cacc += __shfl_xor(cacc, s, 64);
    }
    __shared__ float2 sL[4];
    if (lane == 0) sL[wv] = make_float2(aacc, cacc);
    __syncthreads();
    if (tid == 0) {
        lblk[b] = make_float2(sL[0].x + sL[1].x + sL[2].x + sL[3].x,
                              sL[0].y + sL[1].y + sL[2].y + sL[3].y);
    }
}

// ============ K4: final reduce ============
__global__ __launch_bounds__(NT) void k_final(const float2* __restrict__ lblk,
                                              float* __restrict__ out) {
    int tid = threadIdx.x, lane = tid & 63, wv = tid >> 6;
    double ac = 0, cr = 0;
#pragma unroll
    for (int p = 0; p < NB / NT; ++p) {
        float2 v = lblk[tid + p * NT];
        ac += v.x; cr += v.y;
    }
#pragma unroll
    for (int s = 32; s > 0; s >>= 1) {
        ac += __shfl_xor(ac, s, 64);
        cr += __shfl_xor(cr, s, 64);
    }
    __shared__ double sD[4][2];
    if (lane == 0) { sD[wv][0] = ac; sD[wv][1] = cr; }
    __syncthreads();
    if (tid == 0) {
        ac = sD[0][0] + sD[1][0] + sD[2][0] + sD[3][0];
        cr = sD[0][1] + sD[1][1] + sD[2][1] + sD[3][1];
        out[0] = (float)((-ac + cr) / (double)T_N);
    }
}

extern "C" void kernel_launch(void* const* d_in, const int* in_sizes, int n_in,
                              void* d_out, int out_size, void* d_ws, size_t ws_size,
                              hipStream_t stream) {
    const float* rew = (const float*)d_in[0];
    const float* val = (const float*)d_in[1];
    const float4* blp = (const float4*)d_in[2];
    const float4* act = (const float4*)d_in[3];
    const float4* mu  = (const float4*)d_in[4];
    const float4* lv  = (const float4*)d_in[5];
    const int*   msk = (const int*)d_in[6];

    char* ws = (char*)d_ws;
    float*  stats = (float*)ws;                       // 16 B
    float4* blk   = (float4*)(ws + 256);              // NB*64 = 131072 B
    float2* car   = (float2*)(ws + 256 + NB * 64);    // NB*8  =  16384 B
    float2* lblk  = (float2*)(ws + 256 + NB * 72);    // NB*8  =  16384 B

    k_summ <<<NB, NT, 0, stream>>>(rew, val, msk, blk);
    k_carry<<<1,  NT, 0, stream>>>(blk, car, stats);
    k_main <<<NB, NT, 0, stream>>>(rew, val, msk, act, mu, lv, blp, car, stats, lblk);
    k_final<<<1,  NT, 0, stream>>>(lblk, (float*)d_out);
}

// Round 7
// 195.684 us; speedup vs baseline: 1.0884x; 1.0884x over previous
//
#include <hip/hip_runtime.h>
#include <math.h>

#define T_N 2097152
#define NB 2048                // scan/main grid
#define NT 256
#define EPT 4
#define CHUNK (NT * EPT)       // 1024 elements per block
#define GPT (NB / NT)          // 8 block-summaries per thread in k_carry
#define GAMMA_F 0.99f
#define GL_F (0.99f * 0.95f)
#define LOG2PI_F 1.8378770664093453f

// ws layout (every slot rewritten each launch -> poison-safe):
//   ws +      0 : float stats[4]  (mean_a, inv_a, mean_r, inv_r)
//   ws +    256 : float4 blk[NB*4]   extended block summaries (14 floats padded to 16)
//   ws + 131328 : float2 car[NB]     per-block entering carries (ret, adv)
//   ws + 147712 : float2 lblk[NB]    per-block loss partials (actor, critic)

// ---------------- affine (A,B) pair for both recurrences (k_main) ----------------
struct Aff4 { float ar, br, aa, ba; };
__device__ __forceinline__ Aff4 aff_id() { Aff4 o; o.ar = 1.f; o.br = 0.f; o.aa = 1.f; o.ba = 0.f; return o; }
// L is earlier in time (applied second in the reverse scan): (L o R)(y) = L(R(y))
__device__ __forceinline__ Aff4 aff_compose(const Aff4& L, const Aff4& R) {
    Aff4 o;
    o.ar = L.ar * R.ar;  o.br = fmaf(L.ar, R.br, L.br);
    o.aa = L.aa * R.aa;  o.ba = fmaf(L.aa, R.ba, L.ba);
    return o;
}
__device__ __forceinline__ Aff4 aff_shfl_down(const Aff4& x, int s) {
    Aff4 o;
    o.ar = __shfl_down(x.ar, s, 64); o.br = __shfl_down(x.br, s, 64);
    o.aa = __shfl_down(x.aa, s, 64); o.ba = __shfl_down(x.ba, s, 64);
    return o;
}
__device__ __forceinline__ Aff4 aff_wave_suffix(Aff4 x, int lane) {
#pragma unroll
    for (int s = 1; s < 64; s <<= 1) {
        Aff4 o = aff_shfl_down(x, s);
        if (lane + s < 64) x = aff_compose(x, o);
    }
    return x;
}

// ------------- extended segment: y-map + running sum + running sum-of-squares -------------
// y_out = A*y + B ; Sum(y_t) = P*y + S ; Sum(y_t^2) = U*y^2 + 2*V*y + Q   (y = incoming state)
struct SegF { float A, B, P, S, U, V, Q; };
struct Seg2F { SegF r, a; };
struct SegD { double A, B, P, S, U, V, Q; };
struct Seg2D { SegD r, a; };

__device__ __forceinline__ SegF segf_compose(const SegF& L, const SegF& R) {
    SegF o;
    o.A = L.A * R.A;
    o.B = fmaf(L.A, R.B, L.B);
    o.P = fmaf(L.P, R.A, R.P);
    o.S = fmaf(L.P, R.B, R.S) + L.S;
    float A2 = R.A * R.A, AB = R.A * R.B, B2 = R.B * R.B;
    o.U = fmaf(L.U, A2, R.U);
    o.V = fmaf(L.U, AB, fmaf(L.V, R.A, R.V));
    o.Q = fmaf(L.U, B2, fmaf(2.f * L.V, R.B, R.Q)) + L.Q;
    return o;
}
__device__ __forceinline__ Seg2F seg2f_compose(const Seg2F& L, const Seg2F& R) {
    Seg2F o; o.r = segf_compose(L.r, R.r); o.a = segf_compose(L.a, R.a); return o;
}
__device__ __forceinline__ SegF segf_shfl_down(const SegF& x, int s) {
    SegF o;
    o.A = __shfl_down(x.A, s, 64); o.B = __shfl_down(x.B, s, 64);
    o.P = __shfl_down(x.P, s, 64); o.S = __shfl_down(x.S, s, 64);
    o.U = __shfl_down(x.U, s, 64); o.V = __shfl_down(x.V, s, 64);
    o.Q = __shfl_down(x.Q, s, 64);
    return o;
}
__device__ __forceinline__ Seg2F seg2f_shfl_down(const Seg2F& x, int s) {
    Seg2F o; o.r = segf_shfl_down(x.r, s); o.a = segf_shfl_down(x.a, s); return o;
}

__device__ __forceinline__ SegD segd_id() { SegD o; o.A = 1.0; o.B = 0.0; o.P = 0.0; o.S = 0.0; o.U = 0.0; o.V = 0.0; o.Q = 0.0; return o; }
__device__ __forceinline__ SegD segd_compose(const SegD& L, const SegD& R) {
    SegD o;
    o.A = L.A * R.A;
    o.B = fma(L.A, R.B, L.B);
    o.P = fma(L.P, R.A, R.P);
    o.S = fma(L.P, R.B, R.S) + L.S;
    double A2 = R.A * R.A, AB = R.A * R.B, B2 = R.B * R.B;
    o.U = fma(L.U, A2, R.U);
    o.V = fma(L.U, AB, fma(L.V, R.A, R.V));
    o.Q = fma(L.U, B2, fma(2.0 * L.V, R.B, R.Q)) + L.Q;
    return o;
}
__device__ __forceinline__ Seg2D seg2d_id() { Seg2D o; o.r = segd_id(); o.a = segd_id(); return o; }
__device__ __forceinline__ Seg2D seg2d_compose(const Seg2D& L, const Seg2D& R) {
    Seg2D o; o.r = segd_compose(L.r, R.r); o.a = segd_compose(L.a, R.a); return o;
}
__device__ __forceinline__ SegD segd_shfl_down(const SegD& x, int s) {
    SegD o;
    o.A = __shfl_down(x.A, s, 64); o.B = __shfl_down(x.B, s, 64);
    o.P = __shfl_down(x.P, s, 64); o.S = __shfl_down(x.S, s, 64);
    o.U = __shfl_down(x.U, s, 64); o.V = __shfl_down(x.V, s, 64);
    o.Q = __shfl_down(x.Q, s, 64);
    return o;
}
__device__ __forceinline__ Seg2D seg2d_shfl_down(const Seg2D& x, int s) {
    Seg2D o; o.r = segd_shfl_down(x.r, s); o.a = segd_shfl_down(x.a, s); return o;
}

// Affine-only thread transform over EPT contiguous elements (right-to-left).
__device__ __forceinline__ Aff4 thread_transform(const float rr[EPT], const float vv[EPT],
                                                 const float mm[EPT], float vnext) {
    Aff4 x = aff_id();
    float vn = vnext;
#pragma unroll
    for (int j = EPT - 1; j >= 0; --j) {
        float m = mm[j];
        float gm = GAMMA_F * m;
        x.br = fmaf(gm, x.br, rr[j]);  x.ar = gm * x.ar;              // ret: y = gm*y + r
        float delta = fmaf(GAMMA_F * vn, m, rr[j]) - vv[j];
        float gl = GL_F * m;
        x.ba = fmaf(gl, x.ba, delta);  x.aa = gl * x.aa;              // adv: y = gl*y + delta
        vn = vv[j];
    }
    return x;
}

__device__ __forceinline__ void load4(const float* __restrict__ rew,
                                      const float* __restrict__ val,
                                      const int* __restrict__ msk, int g,
                                      float rr[EPT], float vv[EPT], float mm[EPT],
                                      float& vnext) {
    float4 r4 = *(const float4*)(rew + g);
    float4 v4 = *(const float4*)(val + g);
    int4 m4 = *(const int4*)(msk + g);
    vnext = (g + EPT < T_N) ? val[g + EPT] : 0.f;
    rr[0] = r4.x; rr[1] = r4.y; rr[2] = r4.z; rr[3] = r4.w;
    vv[0] = v4.x; vv[1] = v4.y; vv[2] = v4.z; vv[3] = v4.w;
    mm[0] = (float)m4.x; mm[1] = (float)m4.y; mm[2] = (float)m4.z; mm[3] = (float)m4.w;
}

// ============ K1: extended block summaries ============
__global__ __launch_bounds__(NT, 4) void k_summ(const float* __restrict__ rew,
                                                const float* __restrict__ val,
                                                const int* __restrict__ msk,
                                                float4* __restrict__ blk) {
    int tid = threadIdx.x, lane = tid & 63, wv = tid >> 6;
    int g = blockIdx.x * CHUNK + tid * EPT;
    float rr[EPT], vv[EPT], mm[EPT], vnext;
    load4(rew, val, msk, g, rr, vv, mm, vnext);
    Seg2F x;
    x.r.A = 1.f; x.r.B = 0.f; x.r.P = 0.f; x.r.S = 0.f; x.r.U = 0.f; x.r.V = 0.f; x.r.Q = 0.f;
    x.a = x.r;
    float vn = vnext;
#pragma unroll
    for (int j = EPT - 1; j >= 0; --j) {
        float m = mm[j];
        float ar = GAMMA_F * m, br = rr[j];
        float aa = GL_F * m;
        float delta = fmaf(GAMMA_F * vn, m, rr[j]) - vv[j];
        Seg2F e;
        e.r.A = ar; e.r.B = br; e.r.P = ar; e.r.S = br; e.r.U = ar * ar; e.r.V = ar * br; e.r.Q = br * br;
        e.a.A = aa; e.a.B = delta; e.a.P = aa; e.a.S = delta; e.a.U = aa * aa; e.a.V = aa * delta; e.a.Q = delta * delta;
        x = seg2f_compose(e, x);
        vn = vv[j];
    }
#pragma unroll
    for (int s = 1; s < 64; s <<= 1) {
        Seg2F o = seg2f_shfl_down(x, s);
        x = seg2f_compose(x, o);     // lane i earlier in time than lane i+s
    }
    __shared__ Seg2F sW[4];
    if (lane == 0) sW[wv] = x;
    __syncthreads();
    if (tid == 0) {
        Seg2F t = sW[3];
        t = seg2f_compose(sW[2], t);
        t = seg2f_compose(sW[1], t);
        t = seg2f_compose(sW[0], t);
        int b4 = blockIdx.x * 4;
        blk[b4 + 0] = make_float4(t.r.A, t.r.B, t.r.P, t.r.S);
        blk[b4 + 1] = make_float4(t.r.U, t.r.V, t.r.Q, t.a.A);
        blk[b4 + 2] = make_float4(t.a.B, t.a.P, t.a.S, t.a.U);
        blk[b4 + 3] = make_float4(t.a.V, t.a.Q, 0.f, 0.f);
    }
}

__device__ __forceinline__ Seg2D load_seg(const float4* __restrict__ blk, int idx) {
    float4 q0 = blk[idx * 4 + 0], q1 = blk[idx * 4 + 1];
    float4 q2 = blk[idx * 4 + 2], q3 = blk[idx * 4 + 3];
    Seg2D s;
    s.r.A = q0.x; s.r.B = q0.y; s.r.P = q0.z; s.r.S = q0.w;
    s.r.U = q1.x; s.r.V = q1.y; s.r.Q = q1.z; s.a.A = q1.w;
    s.a.B = q2.x; s.a.P = q2.y; s.a.S = q2.z; s.a.U = q2.w;
    s.a.V = q3.x; s.a.Q = q3.y;
    return s;
}

// ============ K2: single-block carry scan + global stats (f64) ============
__global__ __launch_bounds__(NT) void k_carry(const float4* __restrict__ blk,
                                              float2* __restrict__ car,
                                              float* __restrict__ stats) {
    int tid = threadIdx.x, lane = tid & 63, wv = tid >> 6;
    Seg2D gc = seg2d_id();
#pragma unroll
    for (int p = GPT - 1; p >= 0; --p) gc = seg2d_compose(load_seg(blk, tid * GPT + p), gc);
    Seg2D incl = gc;
#pragma unroll
    for (int s = 1; s < 64; s <<= 1) {
        Seg2D o = seg2d_shfl_down(incl, s);
        if (lane + s < 64) incl = seg2d_compose(incl, o);
    }
    Seg2D ex = seg2d_shfl_down(incl, 1);
    if (lane == 63) ex = seg2d_id();
    __shared__ Seg2D sW[4];
    if (lane == 0) sW[wv] = incl;
    __syncthreads();
    Seg2D tail = seg2d_id();
    for (int w = 3; w > wv; --w) tail = seg2d_compose(sW[w], tail);
    Seg2D H = seg2d_compose(ex, tail);   // composition of all summaries after this thread's group
#pragma unroll
    for (int p = GPT - 1; p >= 0; --p) {
        car[tid * GPT + p] = make_float2((float)H.r.B, (float)H.a.B);  // carry entering block = H(0)
        H = seg2d_compose(load_seg(blk, tid * GPT + p), H);
    }
    if (tid == 0) {
        Seg2D tot = seg2d_compose(incl, tail);   // full composition; y_in = 0
        const double Td = (double)T_N;
        double Sa = tot.a.S, Qa = tot.a.Q, Sr = tot.r.S, Qr = tot.r.Q;
        double va = (Qa - Sa * Sa / Td) / (Td - 1.0);
        double vr = (Qr - Sr * Sr / Td) / (Td - 1.0);
        stats[0] = (float)(Sa / Td);
        stats[1] = (float)(1.0 / (sqrt(va) + 1e-10));
        stats[2] = (float)(Sr / Td);
        stats[3] = (float)(1.0 / (sqrt(vr) + 1e-10));
    }
}

// ============ K3: scan redo + fused loss; LDS bridges scan layout -> lane-dense loss ============
__global__ __launch_bounds__(NT) void k_main(const float* __restrict__ rew,
                                             const float* __restrict__ val,
                                             const int* __restrict__ msk,
                                             const float4* __restrict__ act,
                                             const float4* __restrict__ mu,
                                             const float4* __restrict__ lv,
                                             const float4* __restrict__ blp,
                                             const float2* __restrict__ car,
                                             const float* __restrict__ stats,
                                             float2* __restrict__ lblk) {
    int tid = threadIdx.x, lane = tid & 63, wv = tid >> 6;
    int b = blockIdx.x;
    int g = b * CHUNK + tid * EPT;
    float rr[EPT], vv[EPT], mm[EPT], vnext;
    load4(rew, val, msk, g, rr, vv, mm, vnext);
    Aff4 x = thread_transform(rr, vv, mm, vnext);
    Aff4 incl = aff_wave_suffix(x, lane);
    Aff4 ex = aff_shfl_down(incl, 1);
    if (lane == 63) ex = aff_id();
    __shared__ Aff4 sW[4];
    if (lane == 0) sW[wv] = incl;
    __syncthreads();
    Aff4 tail = aff_id();
    for (int w = 3; w > wv; --w) tail = aff_compose(sW[w], tail);
    ex = aff_compose(ex, tail);
    float2 c = car[b];
    float yr = fmaf(ex.ar, c.x, ex.br);
    float ya = fmaf(ex.aa, c.y, ex.ba);
    float retj[EPT], advj[EPT];
    float vn = vnext;
#pragma unroll
    for (int j = EPT - 1; j >= 0; --j) {
        float m = mm[j];
        float gm = GAMMA_F * m;
        yr = fmaf(gm, yr, rr[j]);  retj[j] = yr;
        float delta = fmaf(GAMMA_F * vn, m, rr[j]) - vv[j];
        ya = fmaf(GL_F * m, ya, delta);  advj[j] = ya;
        vn = vv[j];
    }
    // stage adv/ret/val into LDS in scan layout; read back lane-dense (conflict-free both ways)
    __shared__ float sAdv[CHUNK], sRet[CHUNK], sVal[CHUNK];
    *(float4*)(sAdv + tid * EPT) = make_float4(advj[0], advj[1], advj[2], advj[3]);
    *(float4*)(sRet + tid * EPT) = make_float4(retj[0], retj[1], retj[2], retj[3]);
    *(float4*)(sVal + tid * EPT) = make_float4(vv[0], vv[1], vv[2], vv[3]);
    __syncthreads();

    float mean_a = stats[0], inv_a = stats[1], mean_r = stats[2], inv_r = stats[3];
    // lane-dense loss: thread covers rows b*1024 + tid + k*256 (fully coalesced global loads)
    float4 A[4], M[4], L[4], B[4];
    float AD[4], RT[4], VL[4];
#pragma unroll
    for (int k = 0; k < 4; ++k) {
        int t = b * CHUNK + tid + k * NT;
        A[k] = act[t]; M[k] = mu[t]; L[k] = lv[t]; B[k] = blp[t];
        int r = tid + k * NT;
        AD[k] = sAdv[r]; RT[k] = sRet[r]; VL[k] = sVal[r];
    }
    float aacc = 0.f, cacc = 0.f;
#pragma unroll
    for (int k = 0; k < 4; ++k) {
        float4 a = A[k], m = M[k], l = L[k], bb = B[k];
        float x0 = -0.5f * (a.x - m.x) * (a.x - m.x) * expf(-l.x) - 0.5f * l.x;
        float x1 = -0.5f * (a.y - m.y) * (a.y - m.y) * expf(-l.y) - 0.5f * l.y;
        float x2 = -0.5f * (a.z - m.z) * (a.z - m.z) * expf(-l.z) - 0.5f * l.z;
        float x3 = -0.5f * (a.w - m.w) * (a.w - m.w) * expf(-l.w) - 0.5f * l.w;
        float X = (x0 + x1 + x2 + x3) - (bb.x + bb.y + bb.z + bb.w) - 2.f * LOG2PI_F;
        float ratio = expf(X);
        float rc = fminf(fmaxf(ratio, 0.8f), 1.2f);
        float an = (AD[k] - mean_a) * inv_a;
        aacc += fminf(ratio * an, rc * an);
        float rn = (RT[k] - mean_r) * inv_r;
        float d = VL[k] - rn;
        float adx = fabsf(d);
        cacc += (adx < 1.f) ? 0.5f * d * d : adx - 0.5f;
    }
#pragma unroll
    for (int s = 32; s > 0; s >>= 1) {
        aacc += __shfl_xor(aacc, s, 64);
        cacc += __shfl_xor(cacc, s, 64);
    }
    __shared__ float2 sL[4];
    if (lane == 0) sL[wv] = make_float2(aacc, cacc);
    __syncthreads();
    if (tid == 0) {
        lblk[b] = make_float2(sL[0].x + sL[1].x + sL[2].x + sL[3].x,
                              sL[0].y + sL[1].y + sL[2].y + sL[3].y);
    }
}

// ============ K4: final reduce ============
__global__ __launch_bounds__(NT) void k_final(const float2* __restrict__ lblk,
                                              float* __restrict__ out) {
    int tid = threadIdx.x, lane = tid & 63, wv = tid >> 6;
    double ac = 0, cr = 0;
#pragma unroll
    for (int p = 0; p < NB / NT; ++p) {
        float2 v = lblk[tid + p * NT];
        ac += v.x; cr += v.y;
    }
#pragma unroll
    for (int s = 32; s > 0; s >>= 1) {
        ac += __shfl_xor(ac, s, 64);
        cr += __shfl_xor(cr, s, 64);
    }
    __shared__ double sD[4][2];
    if (lane == 0) { sD[wv][0] = ac; sD[wv][1] = cr; }
    __syncthreads();
    if (tid == 0) {
        ac = sD[0][0] + sD[1][0] + sD[2][0] + sD[3][0];
        cr = sD[0][1] + sD[1][1] + sD[2][1] + sD[3][1];
        out[0] = (float)((-ac + cr) / (double)T_N);
    }
}

extern "C" void kernel_launch(void* const* d_in, const int* in_sizes, int n_in,
                              void* d_out, int out_size, void* d_ws, size_t ws_size,
                              hipStream_t stream) {
    const float* rew = (const float*)d_in[0];
    const float* val = (const float*)d_in[1];
    const float4* blp = (const float4*)d_in[2];
    const float4* act = (const float4*)d_in[3];
    const float4* mu  = (const float4*)d_in[4];
    const float4* lv  = (const float4*)d_in[5];
    const int*   msk = (const int*)d_in[6];

    char* ws = (char*)d_ws;
    float*  stats = (float*)ws;                       // 16 B
    float4* blk   = (float4*)(ws + 256);              // NB*64 = 131072 B
    float2* car   = (float2*)(ws + 256 + NB * 64);    // NB*8  =  16384 B
    float2* lblk  = (float2*)(ws + 256 + NB * 72);    // NB*8  =  16384 B

    k_summ <<<NB, NT, 0, stream>>>(rew, val, msk, blk);
    k_carry<<<1,  NT, 0, stream>>>(blk, car, stats);
    k_main <<<NB, NT, 0, stream>>>(rew, val, msk, act, mu, lv, blp, car, stats, lblk);
    k_final<<<1,  NT, 0, stream>>>(lblk, (float*)d_out);
}

// Round 8
// 184.912 us; speedup vs baseline: 1.1518x; 1.0583x over previous
//
#include <hip/hip_runtime.h>
#include <math.h>

#define T_N 2097152
#define NBM 1024               // blocks for k_summ / k_main
#define NT 256
#define EPT 8
#define CHUNK (NT * EPT)       // 2048 elements per block
#define GPT (NBM / NT)         // 4 block-summaries per thread in k_carry
#define GAMMA_F 0.99f
#define GL_F (0.99f * 0.95f)
#define LOG2PI_F 1.8378770664093453f

// ws layout (every slot rewritten each launch -> poison-safe):
//   ws +     0 : float stats[4]  (mean_a, inv_a, mean_r, inv_r)
//   ws +   256 : float4 blk[NBM*4]   extended block summaries (14 floats padded to 16)
//   ws + 65792 : float2 car[NBM]     per-block entering carries (ret, adv)
//   ws + 73984 : float2 lblk[NBM]    per-block loss partials (actor, critic)

// ---------------- affine (A,B) pair for both recurrences ----------------
struct Aff4 { float ar, br, aa, ba; };
__device__ __forceinline__ Aff4 aff_id() { Aff4 o; o.ar = 1.f; o.br = 0.f; o.aa = 1.f; o.ba = 0.f; return o; }
// L earlier in time (applied second in reverse scan): (L o R)(y) = L(R(y))
__device__ __forceinline__ Aff4 aff_compose(const Aff4& L, const Aff4& R) {
    Aff4 o;
    o.ar = L.ar * R.ar;  o.br = fmaf(L.ar, R.br, L.br);
    o.aa = L.aa * R.aa;  o.ba = fmaf(L.aa, R.ba, L.ba);
    return o;
}
__device__ __forceinline__ Aff4 aff_shfl_down(const Aff4& x, int s) {
    Aff4 o;
    o.ar = __shfl_down(x.ar, s, 64); o.br = __shfl_down(x.br, s, 64);
    o.aa = __shfl_down(x.aa, s, 64); o.ba = __shfl_down(x.ba, s, 64);
    return o;
}
__device__ __forceinline__ Aff4 aff_wave_suffix(Aff4 x, int lane) {
#pragma unroll
    for (int s = 1; s < 64; s <<= 1) {
        Aff4 o = aff_shfl_down(x, s);
        if (lane + s < 64) x = aff_compose(x, o);
    }
    return x;
}

// ------------- extended segment: y-map + running sum + running sum-of-squares -------------
// y_out = A*y + B ; Sum(y_t) = P*y + S ; Sum(y_t^2) = U*y^2 + 2*V*y + Q   (y = incoming state)
struct SegF { float A, B, P, S, U, V, Q; };
struct Seg2F { SegF r, a; };

__device__ __forceinline__ SegF segf_compose(const SegF& L, const SegF& R) {
    SegF o;
    o.A = L.A * R.A;
    o.B = fmaf(L.A, R.B, L.B);
    o.P = fmaf(L.P, R.A, R.P);
    o.S = fmaf(L.P, R.B, R.S) + L.S;
    float A2 = R.A * R.A, AB = R.A * R.B, B2 = R.B * R.B;
    o.U = fmaf(L.U, A2, R.U);
    o.V = fmaf(L.U, AB, fmaf(L.V, R.A, R.V));
    o.Q = fmaf(L.U, B2, fmaf(2.f * L.V, R.B, R.Q)) + L.Q;
    return o;
}
__device__ __forceinline__ Seg2F seg2f_compose(const Seg2F& L, const Seg2F& R) {
    Seg2F o; o.r = segf_compose(L.r, R.r); o.a = segf_compose(L.a, R.a); return o;
}
__device__ __forceinline__ SegF segf_shfl_down(const SegF& x, int s) {
    SegF o;
    o.A = __shfl_down(x.A, s, 64); o.B = __shfl_down(x.B, s, 64);
    o.P = __shfl_down(x.P, s, 64); o.S = __shfl_down(x.S, s, 64);
    o.U = __shfl_down(x.U, s, 64); o.V = __shfl_down(x.V, s, 64);
    o.Q = __shfl_down(x.Q, s, 64);
    return o;
}
__device__ __forceinline__ Seg2F seg2f_shfl_down(const Seg2F& x, int s) {
    Seg2F o; o.r = segf_shfl_down(x.r, s); o.a = segf_shfl_down(x.a, s); return o;
}
__device__ __forceinline__ Seg2F seg2f_id() {
    Seg2F o;
    o.r.A = 1.f; o.r.B = 0.f; o.r.P = 0.f; o.r.S = 0.f; o.r.U = 0.f; o.r.V = 0.f; o.r.Q = 0.f;
    o.a = o.r;
    return o;
}

// Affine-only thread transform over EPT contiguous elements (right-to-left).
__device__ __forceinline__ Aff4 thread_transform(const float rr[EPT], const float vv[EPT],
                                                 const float mm[EPT], float vnext) {
    Aff4 x = aff_id();
    float vn = vnext;
#pragma unroll
    for (int j = EPT - 1; j >= 0; --j) {
        float m = mm[j];
        float gm = GAMMA_F * m;
        x.br = fmaf(gm, x.br, rr[j]);  x.ar = gm * x.ar;              // ret: y = gm*y + r
        float delta = fmaf(GAMMA_F * vn, m, rr[j]) - vv[j];
        float gl = GL_F * m;
        x.ba = fmaf(gl, x.ba, delta);  x.aa = gl * x.aa;              // adv: y = gl*y + delta
        vn = vv[j];
    }
    return x;
}

__device__ __forceinline__ void load8(const float* __restrict__ rew,
                                      const float* __restrict__ val,
                                      const int* __restrict__ msk, int g,
                                      float rr[EPT], float vv[EPT], float mm[EPT],
                                      float& vnext) {
    float4 r0 = *(const float4*)(rew + g);
    float4 r1 = *(const float4*)(rew + g + 4);
    float4 v0 = *(const float4*)(val + g);
    float4 v1 = *(const float4*)(val + g + 4);
    int4 m0 = *(const int4*)(msk + g);
    int4 m1 = *(const int4*)(msk + g + 4);
    vnext = (g + EPT < T_N) ? val[g + EPT] : 0.f;
    rr[0]=r0.x; rr[1]=r0.y; rr[2]=r0.z; rr[3]=r0.w; rr[4]=r1.x; rr[5]=r1.y; rr[6]=r1.z; rr[7]=r1.w;
    vv[0]=v0.x; vv[1]=v0.y; vv[2]=v0.z; vv[3]=v0.w; vv[4]=v1.x; vv[5]=v1.y; vv[6]=v1.z; vv[7]=v1.w;
    mm[0]=(float)m0.x; mm[1]=(float)m0.y; mm[2]=(float)m0.z; mm[3]=(float)m0.w;
    mm[4]=(float)m1.x; mm[5]=(float)m1.y; mm[6]=(float)m1.z; mm[7]=(float)m1.w;
}

// ============ K1: extended block summaries (EPT=8) ============
__global__ __launch_bounds__(NT) void k_summ(const float* __restrict__ rew,
                                             const float* __restrict__ val,
                                             const int* __restrict__ msk,
                                             float4* __restrict__ blk) {
    int tid = threadIdx.x, lane = tid & 63, wv = tid >> 6;
    int g = blockIdx.x * CHUNK + tid * EPT;
    float rr[EPT], vv[EPT], mm[EPT], vnext;
    load8(rew, val, msk, g, rr, vv, mm, vnext);
    Seg2F x = seg2f_id();
    float vn = vnext;
#pragma unroll
    for (int j = EPT - 1; j >= 0; --j) {
        float m = mm[j];
        float ar = GAMMA_F * m, br = rr[j];
        float aa = GL_F * m;
        float delta = fmaf(GAMMA_F * vn, m, rr[j]) - vv[j];
        Seg2F e;
        e.r.A = ar; e.r.B = br; e.r.P = ar; e.r.S = br; e.r.U = ar * ar; e.r.V = ar * br; e.r.Q = br * br;
        e.a.A = aa; e.a.B = delta; e.a.P = aa; e.a.S = delta; e.a.U = aa * aa; e.a.V = aa * delta; e.a.Q = delta * delta;
        x = seg2f_compose(e, x);
        vn = vv[j];
    }
    // ordered down-reduction: lane 0 ends with composition of lanes [0,64)
#pragma unroll
    for (int s = 1; s < 64; s <<= 1) {
        Seg2F o = seg2f_shfl_down(x, s);
        x = seg2f_compose(x, o);
    }
    __shared__ Seg2F sW[4];
    if (lane == 0) sW[wv] = x;
    __syncthreads();
    if (tid == 0) {
        Seg2F t = sW[3];
        t = seg2f_compose(sW[2], t);
        t = seg2f_compose(sW[1], t);
        t = seg2f_compose(sW[0], t);
        int b4 = blockIdx.x * 4;
        blk[b4 + 0] = make_float4(t.r.A, t.r.B, t.r.P, t.r.S);
        blk[b4 + 1] = make_float4(t.r.U, t.r.V, t.r.Q, t.a.A);
        blk[b4 + 2] = make_float4(t.a.B, t.a.P, t.a.S, t.a.U);
        blk[b4 + 3] = make_float4(t.a.V, t.a.Q, 0.f, 0.f);
    }
}

__device__ __forceinline__ Seg2F load_seg(const float4* __restrict__ blk, int idx) {
    float4 q0 = blk[idx * 4 + 0], q1 = blk[idx * 4 + 1];
    float4 q2 = blk[idx * 4 + 2], q3 = blk[idx * 4 + 3];
    Seg2F s;
    s.r.A = q0.x; s.r.B = q0.y; s.r.P = q0.z; s.r.S = q0.w;
    s.r.U = q1.x; s.r.V = q1.y; s.r.Q = q1.z; s.a.A = q1.w;
    s.a.B = q2.x; s.a.P = q2.y; s.a.S = q2.z; s.a.U = q2.w;
    s.a.V = q3.x; s.a.Q = q3.y;
    return s;
}

// ============ K2: single-block carry scan + global stats (f32 compose, f64 finalize) ============
__global__ __launch_bounds__(NT) void k_carry(const float4* __restrict__ blk,
                                              float2* __restrict__ car,
                                              float* __restrict__ stats) {
    int tid = threadIdx.x, lane = tid & 63, wv = tid >> 6;
    Seg2F s[GPT];
#pragma unroll
    for (int p = 0; p < GPT; ++p) s[p] = load_seg(blk, tid * GPT + p);
    Seg2F gc = seg2f_id();
#pragma unroll
    for (int p = GPT - 1; p >= 0; --p) gc = seg2f_compose(s[p], gc);
    Seg2F incl = gc;
#pragma unroll
    for (int ss = 1; ss < 64; ss <<= 1) {
        Seg2F o = seg2f_shfl_down(incl, ss);
        if (lane + ss < 64) incl = seg2f_compose(incl, o);
    }
    Seg2F ex = seg2f_shfl_down(incl, 1);
    if (lane == 63) ex = seg2f_id();
    __shared__ Seg2F sW[4];
    if (lane == 0) sW[wv] = incl;
    __syncthreads();
    Seg2F tail = seg2f_id();
    for (int w = 3; w > wv; --w) tail = seg2f_compose(sW[w], tail);
    Seg2F H = seg2f_compose(ex, tail);   // composition of all summaries after this thread's group
#pragma unroll
    for (int p = GPT - 1; p >= 0; --p) {
        car[tid * GPT + p] = make_float2(H.r.B, H.a.B);   // carry entering block = H(0)
        H = seg2f_compose(s[p], H);
    }
    if (tid == 0) {
        Seg2F tot = seg2f_compose(incl, tail);   // full composition; y_in = 0
        const double Td = (double)T_N;
        double Sa = (double)tot.a.S, Qa = (double)tot.a.Q;
        double Sr = (double)tot.r.S, Qr = (double)tot.r.Q;
        double va = (Qa - Sa * Sa / Td) / (Td - 1.0);
        double vr = (Qr - Sr * Sr / Td) / (Td - 1.0);
        stats[0] = (float)(Sa / Td);
        stats[1] = (float)(1.0 / (sqrt(va) + 1e-10));
        stats[2] = (float)(Sr / Td);
        stats[3] = (float)(1.0 / (sqrt(vr) + 1e-10));
    }
}

// loss math for one float4 row
__device__ __forceinline__ void loss_row(float4 a, float4 m, float4 l, float4 bb,
                                         float AD, float RT, float VL,
                                         float mean_a, float inv_a, float mean_r, float inv_r,
                                         float& aacc, float& cacc) {
    float x0 = -0.5f * (a.x - m.x) * (a.x - m.x) * expf(-l.x) - 0.5f * l.x;
    float x1 = -0.5f * (a.y - m.y) * (a.y - m.y) * expf(-l.y) - 0.5f * l.y;
    float x2 = -0.5f * (a.z - m.z) * (a.z - m.z) * expf(-l.z) - 0.5f * l.z;
    float x3 = -0.5f * (a.w - m.w) * (a.w - m.w) * expf(-l.w) - 0.5f * l.w;
    float X = (x0 + x1 + x2 + x3) - (bb.x + bb.y + bb.z + bb.w) - 2.f * LOG2PI_F;
    float ratio = expf(X);
    float rc = fminf(fmaxf(ratio, 0.8f), 1.2f);
    float an = (AD - mean_a) * inv_a;
    aacc += fminf(ratio * an, rc * an);
    float rn = (RT - mean_r) * inv_r;
    float d = VL - rn;
    float adx = fabsf(d);
    cacc += (adx < 1.f) ? 0.5f * d * d : adx - 0.5f;
}

// ============ K3: scan redo + fused loss, software-pipelined ============
// Loss loads (independent of the scan) are issued FIRST so they are in flight
// during the shuffle-scan + LDS bridge; chunk-B loads issue right after the
// barrier, overlapping chunk-A math.
__global__ __launch_bounds__(NT) void k_main(const float* __restrict__ rew,
                                             const float* __restrict__ val,
                                             const int* __restrict__ msk,
                                             const float4* __restrict__ act,
                                             const float4* __restrict__ mu,
                                             const float4* __restrict__ lv,
                                             const float4* __restrict__ blp,
                                             const float2* __restrict__ car,
                                             const float* __restrict__ stats,
                                             float2* __restrict__ lblk) {
    int tid = threadIdx.x, lane = tid & 63, wv = tid >> 6;
    int b = blockIdx.x;
    int gbase = b * CHUNK;

    // ---- hoisted chunk-A loss loads (rows k=0..3, lane-dense) ----
    float4 A0[4], M0[4], L0[4], B0[4];
#pragma unroll
    for (int k = 0; k < 4; ++k) {
        int t = gbase + tid + k * NT;
        A0[k] = act[t]; M0[k] = mu[t]; L0[k] = lv[t]; B0[k] = blp[t];
    }
    float mean_a = stats[0], inv_a = stats[1], mean_r = stats[2], inv_r = stats[3];
    float2 c = car[b];

    // ---- scan inputs + phase-1 scan ----
    int g = gbase + tid * EPT;
    float rr[EPT], vv[EPT], mm[EPT], vnext;
    load8(rew, val, msk, g, rr, vv, mm, vnext);
    Aff4 x = thread_transform(rr, vv, mm, vnext);
    Aff4 incl = aff_wave_suffix(x, lane);
    Aff4 ex = aff_shfl_down(incl, 1);
    if (lane == 63) ex = aff_id();
    __shared__ Aff4 sW[4];
    if (lane == 0) sW[wv] = incl;
    __syncthreads();
    Aff4 tail = aff_id();
    for (int w = 3; w > wv; --w) tail = aff_compose(sW[w], tail);
    ex = aff_compose(ex, tail);
    float yr = fmaf(ex.ar, c.x, ex.br);
    float ya = fmaf(ex.aa, c.y, ex.ba);
    float retj[EPT], advj[EPT];
    float vn = vnext;
#pragma unroll
    for (int j = EPT - 1; j >= 0; --j) {
        float m = mm[j];
        float gm = GAMMA_F * m;
        yr = fmaf(gm, yr, rr[j]);  retj[j] = yr;
        float delta = fmaf(GAMMA_F * vn, m, rr[j]) - vv[j];
        ya = fmaf(GL_F * m, ya, delta);  advj[j] = ya;
        vn = vv[j];
    }
    // ---- LDS bridge: scan layout -> lane-dense ----
    __shared__ float sAdv[CHUNK], sRet[CHUNK], sVal[CHUNK];
    *(float4*)(sAdv + tid * EPT)     = make_float4(advj[0], advj[1], advj[2], advj[3]);
    *(float4*)(sAdv + tid * EPT + 4) = make_float4(advj[4], advj[5], advj[6], advj[7]);
    *(float4*)(sRet + tid * EPT)     = make_float4(retj[0], retj[1], retj[2], retj[3]);
    *(float4*)(sRet + tid * EPT + 4) = make_float4(retj[4], retj[5], retj[6], retj[7]);
    *(float4*)(sVal + tid * EPT)     = make_float4(vv[0], vv[1], vv[2], vv[3]);
    *(float4*)(sVal + tid * EPT + 4) = make_float4(vv[4], vv[5], vv[6], vv[7]);
    __syncthreads();

    // ---- chunk-B loss loads (rows k=4..7) issued before chunk-A math ----
    float4 A1[4], M1[4], L1[4], B1[4];
#pragma unroll
    for (int k = 0; k < 4; ++k) {
        int t = gbase + tid + (k + 4) * NT;
        A1[k] = act[t]; M1[k] = mu[t]; L1[k] = lv[t]; B1[k] = blp[t];
    }

    float aacc = 0.f, cacc = 0.f;
#pragma unroll
    for (int k = 0; k < 4; ++k) {
        int r = tid + k * NT;
        loss_row(A0[k], M0[k], L0[k], B0[k], sAdv[r], sRet[r], sVal[r],
                 mean_a, inv_a, mean_r, inv_r, aacc, cacc);
    }
#pragma unroll
    for (int k = 0; k < 4; ++k) {
        int r = tid + (k + 4) * NT;
        loss_row(A1[k], M1[k], L1[k], B1[k], sAdv[r], sRet[r], sVal[r],
                 mean_a, inv_a, mean_r, inv_r, aacc, cacc);
    }
#pragma unroll
    for (int s = 32; s > 0; s >>= 1) {
        aacc += __shfl_xor(aacc, s, 64);
        cacc += __shfl_xor(cacc, s, 64);
    }
    __shared__ float2 sL[4];
    if (lane == 0) sL[wv] = make_float2(aacc, cacc);
    __syncthreads();
    if (tid == 0) {
        lblk[b] = make_float2(sL[0].x + sL[1].x + sL[2].x + sL[3].x,
                              sL[0].y + sL[1].y + sL[2].y + sL[3].y);
    }
}

// ============ K4: final reduce ============
__global__ __launch_bounds__(NT) void k_final(const float2* __restrict__ lblk,
                                              float* __restrict__ out) {
    int tid = threadIdx.x, lane = tid & 63, wv = tid >> 6;
    double ac = 0, cr = 0;
#pragma unroll
    for (int p = 0; p < NBM / NT; ++p) {
        float2 v = lblk[tid + p * NT];
        ac += v.x; cr += v.y;
    }
#pragma unroll
    for (int s = 32; s > 0; s >>= 1) {
        ac += __shfl_xor(ac, s, 64);
        cr += __shfl_xor(cr, s, 64);
    }
    __shared__ double sD[4][2];
    if (lane == 0) { sD[wv][0] = ac; sD[wv][1] = cr; }
    __syncthreads();
    if (tid == 0) {
        ac = sD[0][0] + sD[1][0] + sD[2][0] + sD[3][0];
        cr = sD[0][1] + sD[1][1] + sD[2][1] + sD[3][1];
        out[0] = (float)((-ac + cr) / (double)T_N);
    }
}

extern "C" void kernel_launch(void* const* d_in, const int* in_sizes, int n_in,
                              void* d_out, int out_size, void* d_ws, size_t ws_size,
                              hipStream_t stream) {
    const float* rew = (const float*)d_in[0];
    const float* val = (const float*)d_in[1];
    const float4* blp = (const float4*)d_in[2];
    const float4* act = (const float4*)d_in[3];
    const float4* mu  = (const float4*)d_in[4];
    const float4* lv  = (const float4*)d_in[5];
    const int*   msk = (const int*)d_in[6];

    char* ws = (char*)d_ws;
    float*  stats = (float*)ws;                        // 16 B
    float4* blk   = (float4*)(ws + 256);               // NBM*64 = 65536 B
    float2* car   = (float2*)(ws + 256 + NBM * 64);    // NBM*8  =  8192 B
    float2* lblk  = (float2*)(ws + 256 + NBM * 72);    // NBM*8  =  8192 B

    k_summ <<<NBM, NT, 0, stream>>>(rew, val, msk, blk);
    k_carry<<<1,   NT, 0, stream>>>(blk, car, stats);
    k_main <<<NBM, NT, 0, stream>>>(rew, val, msk, act, mu, lv, blp, car, stats, lblk);
    k_final<<<1,   NT, 0, stream>>>(lblk, (float*)d_out);
}